// Round 2
// baseline (471.655 us; speedup 1.0000x reference)
//
#include <hip/hip_runtime.h>

#define LSEQ 1024
#define NDIM 256

// output layout (floats): c_all | y_all | GBT_A | GBT_B
#define O_C 0
#define O_Y (LSEQ * NDIM)                      // 262144
#define O_A (O_Y + LSEQ)                       // 263168
#define O_B (O_A + (size_t)LSEQ * NDIM * NDIM) // 67372032

typedef float v4f __attribute__((ext_vector_type(4)));

static __device__ __forceinline__ float frcp(float x) {
    return __builtin_amdgcn_rcpf(x);
}

// wave-wide shift-right-by-1 via DPP (VALU, no DS pipe).
// lane l gets src from lane l-1; lane 0 gets `inject`.
static __device__ __forceinline__ float dpp_shr1(float inject, float src) {
    int r = __builtin_amdgcn_update_dpp(
        __float_as_int(inject), __float_as_int(src),
        0x138 /* WAVE_SHR1 */, 0xF, 0xF, false);
    return __int_as_float(r);
}

// Opaque register copies: store data lives in registers DISTINCT from the
// scan state (cc/yacc) that is rewritten every tick. Each tick's store data
// stays in its own registers until 8 ticks after the store issued, so the
// compiler's WAR s_waitcnt before redefinition is already satisfied.
static __device__ __forceinline__ v4f stage4(float a, float b, float c, float d) {
    float x0, x1, x2, x3;
    asm volatile("v_mov_b32 %0, %4\n\t"
                 "v_mov_b32 %1, %5\n\t"
                 "v_mov_b32 %2, %6\n\t"
                 "v_mov_b32 %3, %7"
                 : "=&v"(x0), "=&v"(x1), "=&v"(x2), "=&v"(x3)
                 : "v"(a), "v"(b), "v"(c), "v"(d));
    v4f r; r.x = x0; r.y = x1; r.z = x2; r.w = x3;
    return r;
}
static __device__ __forceinline__ float stage1(float a) {
    float x;
    asm volatile("v_mov_b32 %0, %1" : "=&v"(x) : "v"(a));
    return x;
}

__global__ __launch_bounds__(256) void hippo_main(
    const float* __restrict__ f,
    const float* __restrict__ init_state,
    const float* __restrict__ Bvec,   // = r_i = sqrt(2i+1), bit-exact vs reference
    float* __restrict__ out)
{
    const int tid = threadIdx.x;
    const int bid = blockIdx.x;

    if (bid == 0) {
        // ================= sequential scan: systolic over 64 lanes ==========
        // lane l owns elements i = 4l..4l+3. At tick t, lane l performs
        // recurrence step k0 = t - l. Scan state flows lane -> lane+1 each
        // tick via DPP wave_shr1. Stores use the SADDR form with per-slot
        // loop-carried voffset registers: NO address arithmetic in the tick
        // body, and a slot's address/data registers are only redefined 8
        // ticks after its store issued -> no store-retire WAR stall.
        if (tid >= 64) return;
        const int l = tid;
        float rr[4], cc[4];
        #pragma unroll
        for (int e = 0; e < 4; ++e) {
            rr[e] = Bvec[4 * l + e];
            cc[e] = init_state[4 * l + e];
        }
        const float base1 = (float)(4 * l + 1);  // (i+1) for e=0

        float T = 0.0f, S = 0.0f, ssf = 0.0f, yacc = 0.0f;
        // f staged in 64-wide register chunks, rotated every 64 ticks
        float fcur = f[l];
        float fnxt = (64 + l < LSEQ) ? f[64 + l] : 0.0f;

        // 8-deep store staging (one set per tick-slot of the unrolled group)
        v4f   cvb[8];
        float yb[8];
        // per-slot byte offsets off the single SGPR base `out`
        int voff[8], voffY[8];
        #pragma unroll
        for (int g = 0; g < 8; ++g) {
            cvb[g] = (v4f){0.f, 0.f, 0.f, 0.f};
            yb[g] = 0.0f;
            // slot g, group n stores row k0 = 8n+g-l at byte k0*1024 + 16*l.
            // init pre-decremented by the per-group bump (+8192 / +32).
            voff[g]  = (g - l) * 1024 + 16 * l - 8192;
            voffY[g] = 4 * (O_Y + g - 63) - 32;
            // negative/garbage values only ever exist in lanes whose store is
            // exec-masked off by the k0 predicate below.
        }

        for (int tb = 0; tb < LSEQ + 64; tb += 8) {   // ticks tb .. tb+7
            // bump all slot addresses ONCE per group (WAR distance = 8 ticks)
            #pragma unroll
            for (int g = 0; g < 8; ++g) { voff[g] += 8192; voffY[g] += 32; }

            // f-chunk rotation (tb is a multiple of 8; 64 | tb at rotation ticks)
            if ((tb & 63) == 0 && tb) {
                fcur = fnxt;
                int idx = tb + 64 + l;
                fnxt = (idx < LSEQ) ? f[idx] : 0.0f;
            }
            const int fb = tb & 63;

            #pragma unroll
            for (int g = 0; g < 8; ++g) {
                const int t = tb + g;
                // f[t] broadcast: uniform lane index -> scalar readlane (no DS)
                float ft = __int_as_float(
                    __builtin_amdgcn_readlane(__float_as_int(fcur), fb + g));

                const int k0 = t - l;
                const float h  = 0.5f * frcp((float)(k0 + 1));   // lane's ss/2
                const float h0 = 0.5f * frcp((float)(t + 1));    // lane 0's ss/2
                const float ssf0 = 2.0f * h0 * ft;               // ss_t * f_t

                // pipeline handoff (unconditional, all 64 lanes active)
                T    = dpp_shr1(0.0f, T);
                S    = dpp_shr1(0.0f, S);
                yacc = dpp_shr1(0.0f, yacc);
                ssf  = dpp_shr1(ssf0, ssf);

                if (k0 >= 0 && k0 < LSEQ) {
                    #pragma unroll
                    for (int e = 0; e < 4; ++e) {
                        float d    = fmaf(h, base1 + (float)e, 1.0f); // 1 + h(i+1)
                        float invd = frcp(d);
                        // w = (2-d)*c + r*(ssf - h*T)   [P2 row + forcing]
                        float w = fmaf(2.0f - d, cc[e], rr[e] * fmaf(-h, T, ssf));
                        T = fmaf(rr[e], cc[e], T);
                        // forward substitution: c_new = (w - h*r*S)/d
                        float num = fmaf(-h * rr[e], S, w);
                        float cn  = num * invd;
                        S = fmaf(rr[e], cn, S);
                        cc[e] = cn;
                    }
                    yacc += (cc[0] + cc[1]) + (cc[2] + cc[3]);
                    // stage through opaque copies, store via SADDR + stable voff
                    cvb[g] = stage4(cc[0], cc[1], cc[2], cc[3]);
                    asm volatile("global_store_dwordx4 %0, %1, %2"
                                 :: "v"(voff[g]), "v"(cvb[g]), "s"(out));
                    yb[g] = stage1(yacc);
                    if (l == 63) {
                        asm volatile("global_store_dword %0, %1, %2"
                                     :: "v"(voffY[g]), "v"(yb[g]), "s"(out));
                    }
                }
            }
            // Liveness anchor: keep all 8 stage sets in distinct registers
            // until group end, so slot g's registers are first redefined a
            // full group after its store issued.
            asm volatile("" ::
                "v"(cvb[0]), "v"(cvb[1]), "v"(cvb[2]), "v"(cvb[3]),
                "v"(cvb[4]), "v"(cvb[5]), "v"(cvb[6]), "v"(cvb[7]),
                "v"(yb[0]), "v"(yb[1]), "v"(yb[2]), "v"(yb[3]),
                "v"(yb[4]), "v"(yb[5]), "v"(yb[6]), "v"(yb[7]));
        }
    } else {
        // ================= GBT_A / GBT_B for k = bid-1 ======================
        // P1 = I - h A lower-triangular semiseparable; M = P1^{-1} has
        // M[i,i] = 1/d_i, M[i,j] = -h r_i r_j/(d_i d_j) * prod_{m=j+1}^{i-1} g_m,
        // g_m = (1 - h m)/d_m.  Ad = 2M - I.
        const int k = bid - 1;
        const int lane = tid & 63;
        const int wave = tid >> 6;
        const float kp = (float)(k + 1);
        const float ss = 1.0f / kp;
        const float h  = 0.5f * ss;

        __shared__ float s_r[NDIM], s_invd[NDIM], s_rowco[NDIM], s_g[NDIM], s_diag[NDIM];
        {
            int i = tid;                           // 256 threads, 256 elements
            float r    = Bvec[i];
            float d    = fmaf(h, (float)(i + 1), 1.0f);
            float invd = 1.0f / d;
            s_r[i]     = r;
            s_invd[i]  = invd;
            s_rowco[i] = -2.0f * h * r * invd;     // 2 * (-h r_i / d_i)
            s_g[i]     = (1.0f - h * (float)i) * invd;
            s_diag[i]  = fmaf(2.0f, invd, -1.0f);  // 2/d_i - 1
        }
        __syncthreads();

        // ---- GBT_B, closed form: Bd_i = ss * r_i * invd_i * prod_{j<i} g_j.
        // 256 threads, one output each; issued early so the store overlaps
        // the A-row walk below.
        {
            float Pi = 1.0f;
            for (int j = 0; j < NDIM - 1; ++j) {
                float gj = s_g[j];                 // uniform LDS broadcast
                Pi *= (j < tid) ? gj : 1.0f;
            }
            float* outB = out + O_B + (size_t)k * NDIM;
            outB[tid] = ss * s_r[tid] * s_invd[tid] * Pi;
        }

        // lane owns columns j = 4*lane..4*lane+3; per-column running state
        float colc[4], Scol[4] = {0.f, 0.f, 0.f, 0.f};
        #pragma unroll
        for (int e = 0; e < 4; ++e) {
            int j = 4 * lane + e;
            colc[e] = s_r[j] * s_invd[j];          // start value when row passes j
        }

        const int i0 = wave * 64;
        // ---- recurrence-only rows [0, i0): advance column state, no stores
        for (int i = 0; i < i0; ++i) {
            float g = s_g[i];
            #pragma unroll
            for (int e = 0; e < 4; ++e) {
                int j = 4 * lane + e;
                if (j < i)       Scol[e] *= g;
                else if (j == i) Scol[e] = colc[e];
            }
        }
        // ---- owned rows [i0, i0+64): compute + nontemporal store
        float* outA = out + O_A + (size_t)k * (NDIM * NDIM) + 4 * lane;
        for (int i = i0; i < i0 + 64; ++i) {
            float rowco = s_rowco[i];
            float g     = s_g[i];
            float dg    = s_diag[i];
            float v[4];
            #pragma unroll
            for (int e = 0; e < 4; ++e) {
                int j = 4 * lane + e;
                if (j < i) {
                    v[e] = rowco * Scol[e];
                    Scol[e] *= g;
                } else if (j == i) {
                    v[e] = dg;
                    Scol[e] = colc[e];
                } else {
                    v[e] = 0.0f;
                }
            }
            v4f vv = { v[0], v[1], v[2], v[3] };
            __builtin_nontemporal_store(
                vv, reinterpret_cast<v4f*>(outA + (size_t)i * NDIM));
        }
    }
}

extern "C" void kernel_launch(void* const* d_in, const int* in_sizes, int n_in,
                              void* d_out, int out_size, void* d_ws, size_t ws_size,
                              hipStream_t stream) {
    (void)in_sizes; (void)n_in; (void)d_ws; (void)ws_size; (void)out_size;
    const float* f    = (const float*)d_in[0];
    const float* init = (const float*)d_in[1];
    const float* Bv   = (const float*)d_in[3];   // B = r[:,None]
    float* outp       = (float*)d_out;
    hippo_main<<<1 + LSEQ, 256, 0, stream>>>(f, init, Bv, outp);
}

// Round 3
// 449.520 us; speedup vs baseline: 1.0492x; 1.0492x over previous
//
#include <hip/hip_runtime.h>

#define LSEQ 1024
#define NDIM 256

// output layout (floats): c_all | y_all | GBT_A | GBT_B
#define O_C 0
#define O_Y (LSEQ * NDIM)                      // 262144
#define O_A (O_Y + LSEQ)                       // 263168
#define O_B (O_A + (size_t)LSEQ * NDIM * NDIM) // 67372032

#define RING 128        // LDS ring slots (power of 2, >= 64 skew + 8 group + lag)
#define NGRP 136        // compute groups of 8 ticks: ticks 0 .. 1087

typedef float v4f __attribute__((ext_vector_type(4)));

static __device__ __forceinline__ float frcp(float x) {
    return __builtin_amdgcn_rcpf(x);
}

// wave-wide shift-right-by-1 via DPP (VALU, no DS pipe).
// lane l gets src from lane l-1; lane 0 gets `inject`.
static __device__ __forceinline__ float dpp_shr1(float inject, float src) {
    int r = __builtin_amdgcn_update_dpp(
        __float_as_int(inject), __float_as_int(src),
        0x138 /* WAVE_SHR1 */, 0xF, 0xF, false);
    return __int_as_float(r);
}

__global__ __launch_bounds__(256) void hippo_main(
    const float* __restrict__ f,
    const float* __restrict__ init_state,
    const float* __restrict__ Bvec,   // = r_i = sqrt(2i+1), bit-exact vs reference
    float* __restrict__ out)
{
    const int tid = threadIdx.x;
    const int bid = blockIdx.x;

    if (bid == 0) {
        // ================= sequential scan, producer/consumer ===============
        // Wave 0: systolic scan over 64 lanes (lane l owns elements 4l..4l+3;
        //   at tick t it performs recurrence step k0 = t-l). It touches ONLY
        //   LDS: tick t's 1KB of c-fragments go to ring slot (t & 127)
        //   (wave-uniform slot -> structural-minimum LDS banking), y to y_lds,
        //   f comes from a preloaded f_lds. Zero VMEM on the critical wave ->
        //   no store-ack/vmcnt stalls ever.
        // Waves 1-3: store engines. Every 8-tick group (one __syncthreads
        //   cadence) they gather the 8 rows completed last group from the
        //   ring (per-lane slot (r+lane)&127) and issue coalesced 1KB stores.
        // The ~141KB LDS footprint also means no GBT block can co-reside on
        // this CU -> the scan wave owns a SIMD outright.
        __shared__ float c_ring[RING * NDIM];   // 128 KiB
        __shared__ float y_lds[LSEQ];           // 4 KiB
        __shared__ float f_lds[LSEQ];           // 4 KiB

        // cooperative f preload (all 256 threads)
        for (int i = tid; i < LSEQ; i += 256) f_lds[i] = f[i];
        __syncthreads();

        if (tid < 64) {
            // ---------------- wave 0: the scan ----------------
            const int l = tid;
            float rr[4], cc[4];
            #pragma unroll
            for (int e = 0; e < 4; ++e) {
                rr[e] = Bvec[4 * l + e];
                cc[e] = init_state[4 * l + e];
            }
            const float base1 = (float)(4 * l + 1);  // (i+1) for e=0

            float T = 0.0f, S = 0.0f, ssf = 0.0f, yacc = 0.0f;
            float fcur = f_lds[l];
            float fnxt = f_lds[64 + l];

            for (int grp = 0; grp <= NGRP; ++grp) {
                if (grp < NGRP) {
                    const int tb = grp * 8;
                    if ((tb & 63) == 0 && tb) {
                        fcur = fnxt;
                        int nb = tb + 64;                     // next chunk base
                        fnxt = f_lds[(nb < LSEQ ? nb : 0) + l]; // clamp: unused
                    }
                    const int fb = tb & 63;

                    #pragma unroll
                    for (int g = 0; g < 8; ++g) {
                        const int t = tb + g;
                        float ft = __int_as_float(
                            __builtin_amdgcn_readlane(__float_as_int(fcur), fb + g));

                        const int k0 = t - l;
                        const float h  = 0.5f * frcp((float)(k0 + 1)); // lane ss/2
                        const float h0 = 0.5f * frcp((float)(t + 1));  // lane0 ss/2
                        const float ssf0 = 2.0f * h0 * ft;             // ss_t * f_t

                        // pipeline handoff (unconditional, all 64 lanes)
                        T    = dpp_shr1(0.0f, T);
                        S    = dpp_shr1(0.0f, S);
                        yacc = dpp_shr1(0.0f, yacc);
                        ssf  = dpp_shr1(ssf0, ssf);

                        if (k0 >= 0 && k0 < LSEQ) {
                            #pragma unroll
                            for (int e = 0; e < 4; ++e) {
                                float d    = fmaf(h, base1 + (float)e, 1.0f);
                                float invd = frcp(d);
                                // w = (2-d)*c + r*(ssf - h*T)
                                float w = fmaf(2.0f - d, cc[e],
                                               rr[e] * fmaf(-h, T, ssf));
                                T = fmaf(rr[e], cc[e], T);
                                // forward substitution: c_new = (w - h*r*S)/d
                                float num = fmaf(-h * rr[e], S, w);
                                float cn  = num * invd;
                                S = fmaf(rr[e], cn, S);
                                cc[e] = cn;
                            }
                            yacc += (cc[0] + cc[1]) + (cc[2] + cc[3]);
                            const int slot = t & (RING - 1);   // wave-uniform
                            v4f cv = { cc[0], cc[1], cc[2], cc[3] };
                            *reinterpret_cast<v4f*>(
                                &c_ring[slot * NDIM + 4 * l]) = cv;
                            if (l == 63) y_lds[k0] = yacc;
                        }
                    }
                }
                __syncthreads();
            }
        } else {
            // ---------------- waves 1-3: store engines ----------------
            const int wave = tid >> 6;        // 1..3
            const int lane = tid & 63;
            for (int grp = 0; grp <= NGRP; ++grp) {
                const int tb = grp * 8;
                // rows completed by end of previous group: k0 <= tb-64.
                // this iteration flushes [tb-71, tb-64] (8 rows, contiguous
                // across iterations; clamped at both ends).
                #pragma unroll
                for (int ri = 0; ri < 8; ++ri) {
                    if (ri / 3 != wave - 1) continue; // w1:0-2 w2:3-5 w3:6-7
                    int r = tb - 71 + ri;
                    if (r < 0 || r >= LSEQ) continue;
                    int slot = (r + lane) & (RING - 1);
                    v4f d = *reinterpret_cast<const v4f*>(
                        &c_ring[slot * NDIM + 4 * lane]);
                    *reinterpret_cast<v4f*>(
                        out + O_C + (size_t)r * NDIM + 4 * lane) = d;
                    if (lane == 0) out[O_Y + r] = y_lds[r];
                }
                __syncthreads();
            }
        }
    } else {
        // ================= GBT_A / GBT_B for k = bid-1 ======================
        // P1 = I - h A lower-triangular semiseparable; M = P1^{-1} has
        // M[i,i] = 1/d_i, M[i,j] = -h r_i r_j/(d_i d_j) * prod_{m=j+1}^{i-1} g_m,
        // g_m = (1 - h m)/d_m.  Ad = 2M - I.
        const int k = bid - 1;
        const int lane = tid & 63;
        const int wave = tid >> 6;
        const float kp = (float)(k + 1);
        const float ss = 1.0f / kp;
        const float h  = 0.5f * ss;

        __shared__ float s_r[NDIM], s_invd[NDIM], s_rowco[NDIM], s_g[NDIM], s_diag[NDIM];
        {
            int i = tid;                           // 256 threads, 256 elements
            float r    = Bvec[i];
            float d    = fmaf(h, (float)(i + 1), 1.0f);
            float invd = 1.0f / d;
            s_r[i]     = r;
            s_invd[i]  = invd;
            s_rowco[i] = -2.0f * h * r * invd;     // 2 * (-h r_i / d_i)
            s_g[i]     = (1.0f - h * (float)i) * invd;
            s_diag[i]  = fmaf(2.0f, invd, -1.0f);  // 2/d_i - 1
        }
        __syncthreads();

        // ---- GBT_B, closed form: Bd_i = ss * r_i * invd_i * prod_{j<i} g_j.
        {
            float Pi = 1.0f;
            for (int j = 0; j < NDIM - 1; ++j) {
                float gj = s_g[j];                 // uniform LDS broadcast
                Pi *= (j < tid) ? gj : 1.0f;
            }
            float* outB = out + O_B + (size_t)k * NDIM;
            outB[tid] = ss * s_r[tid] * s_invd[tid] * Pi;
        }

        // lane owns columns j = 4*lane..4*lane+3; per-column running state
        float colc[4], Scol[4] = {0.f, 0.f, 0.f, 0.f};
        #pragma unroll
        for (int e = 0; e < 4; ++e) {
            int j = 4 * lane + e;
            colc[e] = s_r[j] * s_invd[j];          // start value when row passes j
        }

        const int i0 = wave * 64;
        // ---- recurrence-only rows [0, i0): advance column state, no stores
        for (int i = 0; i < i0; ++i) {
            float g = s_g[i];
            #pragma unroll
            for (int e = 0; e < 4; ++e) {
                int j = 4 * lane + e;
                if (j < i)       Scol[e] *= g;
                else if (j == i) Scol[e] = colc[e];
            }
        }
        // ---- owned rows [i0, i0+64): compute + nontemporal store
        float* outA = out + O_A + (size_t)k * (NDIM * NDIM) + 4 * lane;
        for (int i = i0; i < i0 + 64; ++i) {
            float rowco = s_rowco[i];
            float g     = s_g[i];
            float dg    = s_diag[i];
            float v[4];
            #pragma unroll
            for (int e = 0; e < 4; ++e) {
                int j = 4 * lane + e;
                if (j < i) {
                    v[e] = rowco * Scol[e];
                    Scol[e] *= g;
                } else if (j == i) {
                    v[e] = dg;
                    Scol[e] = colc[e];
                } else {
                    v[e] = 0.0f;
                }
            }
            v4f vv = { v[0], v[1], v[2], v[3] };
            __builtin_nontemporal_store(
                vv, reinterpret_cast<v4f*>(outA + (size_t)i * NDIM));
        }
    }
}

extern "C" void kernel_launch(void* const* d_in, const int* in_sizes, int n_in,
                              void* d_out, int out_size, void* d_ws, size_t ws_size,
                              hipStream_t stream) {
    (void)in_sizes; (void)n_in; (void)d_ws; (void)ws_size; (void)out_size;
    const float* f    = (const float*)d_in[0];
    const float* init = (const float*)d_in[1];
    const float* Bv   = (const float*)d_in[3];   // B = r[:,None]
    float* outp       = (float*)d_out;
    hippo_main<<<1 + LSEQ, 256, 0, stream>>>(f, init, Bv, outp);
}

// Round 6
// 383.576 us; speedup vs baseline: 1.2296x; 1.1719x over previous
//
#include <hip/hip_runtime.h>

#define LSEQ 1024
#define NDIM 256

// output layout (floats): c_all | y_all | GBT_A | GBT_B
#define O_C 0
#define O_Y (LSEQ * NDIM)                      // 262144
#define O_A (O_Y + LSEQ)                       // 263168
#define O_B (O_A + (size_t)LSEQ * NDIM * NDIM) // 67372032

#define RING 128     // LDS ring slots
#define GT   16      // ticks per barrier group
#define NGRP 68      // compute groups (ticks 0..1087); group 68 is flush-only

typedef float v4f __attribute__((ext_vector_type(4)));

static __device__ __forceinline__ float frcp(float x) {
    return __builtin_amdgcn_rcpf(x);
}
// HW log2 / exp2 (v_log_f32 / v_exp_f32)
static __device__ __forceinline__ float hlog2(float x) {
    return __builtin_amdgcn_logf(x);
}
static __device__ __forceinline__ float hexp2(float x) {
    return __builtin_amdgcn_exp2f(x);
}

// in-place wave shift-right-by-1, lane 0 := 0 (bound_ctrl zero-fill) — 1 instr
static __device__ __forceinline__ float dpp_shr1_z(float x) {
    int r = __builtin_amdgcn_update_dpp(
        __float_as_int(x), __float_as_int(x), 0x138 /*WAVE_SHR1*/, 0xF, 0xF, true);
    return __int_as_float(r);
}
// shift-right-by-1 with lane 0 := inject (old-operand form) — 2 instr
static __device__ __forceinline__ float dpp_shr1_inj(float inject, float src) {
    int r = __builtin_amdgcn_update_dpp(
        __float_as_int(inject), __float_as_int(src), 0x138, 0xF, 0xF, false);
    return __int_as_float(r);
}

__global__ __launch_bounds__(256) void hippo_main(
    const float* __restrict__ f,
    const float* __restrict__ init_state,
    const float* __restrict__ Bvec,   // = r_i = sqrt(2i+1)
    float* __restrict__ out)
{
    const int tid = threadIdx.x;
    const int bid = blockIdx.x;

    if (bid == 0) {
        // ================= sequential scan, producer/consumer ===============
        // Wave 0: 64-lane systolic scan, LDS-only, bit-identical math to R0-R3
        // but with a trimmed tick: 1-instr DPP shifts, h = rcp(E) with E
        // tracked incrementally (rcp(2x)==0.5*rcp(x) bit-exact), per-chunk
        // precomputed ssfv (inject = readlane only), and a de-predicated
        // steady phase (ticks 64..1023). Barriers every 16 ticks.
        // Waves 1-3: store engines flushing 16 rows/group from the LDS ring.
        __shared__ float c_ring[RING * NDIM];   // 128 KiB
        __shared__ float y_lds[LSEQ];           // 4 KiB
        __shared__ float f_lds[LSEQ];           // 4 KiB

        for (int i = tid; i < LSEQ; i += 256) f_lds[i] = f[i];
        __syncthreads();

        if (tid < 64) {
            const int l = tid;
            float rr[4], cc[4], baseE[4];
            #pragma unroll
            for (int e = 0; e < 4; ++e) {
                rr[e] = Bvec[4 * l + e];
                cc[e] = init_state[4 * l + e];
                baseE[e] = (float)(4 * l + 1 + e);   // (i+1)
            }
            float T = 0.0f, S = 0.0f, ssf = 0.0f, yacc = 0.0f;
            float E = (float)(-2 * l);               // E = 2(k0+1) after +=2
            float fcur = f_lds[l];
            float fnxt = f_lds[64 + l];
            float ssfv = fcur * frcp((float)(l + 1)); // ss_t*f_t for chunk 0

// PHASE: 0 = ramp-up (act iff t>=l), 1 = steady (all), 2 = ramp-down (t-l<LSEQ)
#define SCAN_TICK(T_, PHASE)                                                  \
  {                                                                           \
    const int t_ = (T_);                                                      \
    float inj = __int_as_float(__builtin_amdgcn_readlane(                     \
        __float_as_int(ssfv), t_ & 63));                                      \
    T    = dpp_shr1_z(T);                                                     \
    S    = dpp_shr1_z(S);                                                     \
    yacc = dpp_shr1_z(yacc);                                                  \
    ssf  = dpp_shr1_inj(inj, ssf);                                            \
    E += 2.0f;                                                                \
    float h = frcp(E);                                                        \
    bool act = (PHASE == 1) ||                                                \
               ((PHASE == 0) ? (t_ >= l) : (t_ - l < LSEQ));                  \
    if (act) {                                                                \
      _Pragma("unroll")                                                       \
      for (int e = 0; e < 4; ++e) {                                           \
        float d    = fmaf(h, baseE[e], 1.0f);                                 \
        float invd = frcp(d);                                                 \
        float w    = fmaf(2.0f - d, cc[e], rr[e] * fmaf(-h, T, ssf));         \
        T = fmaf(rr[e], cc[e], T);                                            \
        float num = fmaf(-h * rr[e], S, w);                                   \
        float cn  = num * invd;                                               \
        S = fmaf(rr[e], cn, S);                                               \
        cc[e] = cn;                                                           \
      }                                                                       \
      yacc += (cc[0] + cc[1]) + (cc[2] + cc[3]);                              \
      v4f cv = { cc[0], cc[1], cc[2], cc[3] };                                \
      *reinterpret_cast<v4f*>(&c_ring[(t_ & (RING - 1)) * NDIM + 4 * l]) = cv;\
      if (l == 63) y_lds[t_ - 63] = yacc;                                     \
    }                                                                         \
  }

            int grp = 0;
            for (; grp < 4; ++grp) {                 // ticks 0..63
                const int tb = grp * GT;
                #pragma unroll
                for (int g = 0; g < GT; ++g) SCAN_TICK(tb + g, 0);
                __syncthreads();
            }
            for (; grp < 64; ++grp) {                // ticks 64..1023
                const int tb = grp * GT;
                if ((tb & 63) == 0) {                // chunk rotation
                    fcur = fnxt;
                    int idx = tb + 64 + l;
                    fnxt = f_lds[(idx < LSEQ) ? idx : 0];
                    ssfv = fcur * frcp((float)(tb + l + 1));
                }
                #pragma unroll
                for (int g = 0; g < GT; ++g) SCAN_TICK(tb + g, 1);
                __syncthreads();
            }
            for (; grp < NGRP; ++grp) {              // ticks 1024..1087
                const int tb = grp * GT;
                #pragma unroll
                for (int g = 0; g < GT; ++g) SCAN_TICK(tb + g, 2);
                __syncthreads();
            }
            __syncthreads();                         // match flush grp 68
#undef SCAN_TICK
        } else {
            // ---------------- waves 1-3: store engines ----------------
            const int wv = tid >> 6;          // 1..3
            const int lane = tid & 63;
            for (int grp = 0; grp <= NGRP; ++grp) {
                const int r0 = grp * GT - 80; // rows r0..r0+15 (completed)
                const int lo = (wv == 1) ? 0 : (wv == 2) ? 6 : 11;
                const int hi = (wv == 1) ? 5 : (wv == 2) ? 10 : 15;
                for (int ri = lo; ri <= hi; ++ri) {
                    int r = r0 + ri;
                    if (r >= 0 && r < LSEQ) {
                        int slot = (r + lane) & (RING - 1);
                        v4f dv = *reinterpret_cast<const v4f*>(
                            &c_ring[slot * NDIM + 4 * lane]);
                        __builtin_nontemporal_store(dv,
                            reinterpret_cast<v4f*>(
                                out + O_C + (size_t)r * NDIM + 4 * lane));
                    }
                }
                if (wv == 3 && lane < GT) {
                    int r = r0 + lane;
                    if (r >= 0 && r < LSEQ)
                        __builtin_nontemporal_store(y_lds[r], out + O_Y + r);
                }
                __syncthreads();
            }
        }
    } else {
        // ================= GBT_A / GBT_B for k = bid-1, closed form =========
        // M[i,j] = -h r_i r_j/(d_i d_j) * W(j+1,i-1), W = P(i-1)/P(j),
        // P(p) = prod_{m<=p} g_m, g_m = (1-h m)/d_m.  Ad = 2M - I.
        // P ratios via log2-space prefix sums (underflow-safe); exact zeros
        // and signs tracked structurally in a packed int prefix.
        const int k = bid - 1;
        const int lane = tid & 63;
        const int wave = tid >> 6;
        const float kp = (float)(k + 1);
        const float ss = 1.0f / kp;
        const float h  = 0.5f * ss;

        __shared__ float s_cc[NDIM], s_rowco[NDIM], s_diag[NDIM], s_Lp[NDIM];
        __shared__ int   s_NZp[NDIM];
        __shared__ float s_wL[4];
        __shared__ int   s_wNZ[4];

        const int i = tid;
        const float r    = Bvec[i];
        const float dd   = fmaf(h, (float)(i + 1), 1.0f);
        const float invd = 1.0f / dd;
        const float g    = (1.0f - h * (float)i) * invd;

        const int zer = (g == 0.0f) ? 1 : 0;
        const int neg = (g < 0.0f) ? 1 : 0;
        float sL = zer ? 0.0f : hlog2(fabsf(g));
        int   sNZ = neg | (zer << 16);

        // inclusive scan: intra-wave shfl + cross-wave totals
        #pragma unroll
        for (int off = 1; off < 64; off <<= 1) {
            float tL  = __shfl_up(sL, off);
            int   tNZ = __shfl_up(sNZ, off);
            if (lane >= off) { sL += tL; sNZ += tNZ; }
        }
        if (lane == 63) { s_wL[wave] = sL; s_wNZ[wave] = sNZ; }
        __syncthreads();
        for (int ww = 0; ww < wave; ++ww) { sL += s_wL[ww]; sNZ += s_wNZ[ww]; }

        s_Lp[i]    = sL;
        s_NZp[i]   = sNZ;
        s_cc[i]    = r * invd;
        s_rowco[i] = -2.0f * h * r * invd;     // = -ss*r*invd
        s_diag[i]  = fmaf(2.0f, invd, -1.0f);
        __syncthreads();

        // GBT_B: Bd_i = ss*r_i*invd_i * P(i-1) = -rowco_i * P(i-1)
        {
            float P;
            if (i == 0) P = 1.0f;
            else {
                float Lw = s_Lp[i - 1]; int nzw = s_NZp[i - 1];
                P = (nzw >> 16) ? 0.0f : hexp2(Lw);
                if (nzw & 1) P = -P;
            }
            out[O_B + (size_t)k * NDIM + i] = -s_rowco[i] * P;
        }

        // per-lane column constants (fixed across rows)
        float Lj[4], ccj[4]; int NZj[4];
        #pragma unroll
        for (int e = 0; e < 4; ++e) {
            int j = 4 * lane + e;
            Lj[e]  = s_Lp[j];
            NZj[e] = s_NZp[j];
            ccj[e] = s_cc[j];
        }

        const int i0 = wave * 64;
        float* outA = out + O_A + (size_t)k * (NDIM * NDIM) + 4 * lane;
        #pragma unroll 4
        for (int ir = 0; ir < 64; ++ir) {
            const int irow = i0 + ir;
            const int ip = (irow > 0) ? (irow - 1) : 0;
            const float Lpi = s_Lp[ip];
            const int   NZi = s_NZp[ip];
            const float rc  = s_rowco[irow];
            const float dg  = s_diag[irow];
            float v[4];
            #pragma unroll
            for (int e = 0; e < 4; ++e) {
                const int j = 4 * lane + e;
                float wv = hexp2(Lpi - Lj[e]);
                int nzd = NZi - NZj[e];
                wv = (nzd >> 16) ? 0.0f : wv;
                wv = (nzd & 1) ? -wv : wv;
                float val = rc * ccj[e] * wv;
                v[e] = (j < irow) ? val : ((j == irow) ? dg : 0.0f);
            }
            v4f vv = { v[0], v[1], v[2], v[3] };
            __builtin_nontemporal_store(
                vv, reinterpret_cast<v4f*>(outA + (size_t)irow * NDIM));
        }
    }
}

extern "C" void kernel_launch(void* const* d_in, const int* in_sizes, int n_in,
                              void* d_out, int out_size, void* d_ws, size_t ws_size,
                              hipStream_t stream) {
    (void)in_sizes; (void)n_in; (void)d_ws; (void)ws_size; (void)out_size;
    const float* f    = (const float*)d_in[0];
    const float* init = (const float*)d_in[1];
    const float* Bv   = (const float*)d_in[3];   // B = r[:,None]
    float* outp       = (float*)d_out;
    hippo_main<<<1 + LSEQ, 256, 0, stream>>>(f, init, Bv, outp);
}

// Round 7
// 383.264 us; speedup vs baseline: 1.2306x; 1.0008x over previous
//
#include <hip/hip_runtime.h>

#define LSEQ 1024
#define NDIM 256

// output layout (floats): c_all | y_all | GBT_A | GBT_B
#define O_C 0
#define O_Y (LSEQ * NDIM)                      // 262144
#define O_A (O_Y + LSEQ)                       // 263168
#define O_B (O_A + (size_t)LSEQ * NDIM * NDIM) // 67372032

#define RING 128     // LDS ring slots
#define GT   16      // ticks per progress-publish group

typedef float v4f __attribute__((ext_vector_type(4)));

static __device__ __forceinline__ float frcp(float x) {
    return __builtin_amdgcn_rcpf(x);
}
// HW log2 / exp2 (v_log_f32 / v_exp_f32)
static __device__ __forceinline__ float hlog2(float x) {
    return __builtin_amdgcn_logf(x);
}
static __device__ __forceinline__ float hexp2(float x) {
    return __builtin_amdgcn_exp2f(x);
}

// in-place wave shift-right-by-1, lane 0 := 0 (bound_ctrl zero-fill) — 1 instr
static __device__ __forceinline__ float dpp_shr1_z(float x) {
    int r = __builtin_amdgcn_update_dpp(
        __float_as_int(x), __float_as_int(x), 0x138 /*WAVE_SHR1*/, 0xF, 0xF, true);
    return __int_as_float(r);
}
// shift-right-by-1 with lane 0 := inject (old-operand form)
static __device__ __forceinline__ float dpp_shr1_inj(float inject, float src) {
    int r = __builtin_amdgcn_update_dpp(
        __float_as_int(inject), __float_as_int(src), 0x138, 0xF, 0xF, false);
    return __int_as_float(r);
}

__global__ __launch_bounds__(256) void hippo_main(
    const float* __restrict__ f,
    const float* __restrict__ init_state,
    const float* __restrict__ Bvec,   // = r_i = sqrt(2i+1)
    float* __restrict__ out)
{
    const int tid = threadIdx.x;
    const int bid = blockIdx.x;

    if (bid == 0) {
        // ======== sequential scan, barrier-free producer/consumer ===========
        // Wave 0 (scan): 64-lane systolic, LDS-only, bit-identical math to R6.
        //   Publishes s_prog = completed-tick count every 16 ticks
        //   (lgkmcnt(0) + ds_write). NEVER executes a barrier or VMEM op in
        //   its loop -> no store-drain coupling, no barrier waits.
        // Waves 1-3 (flush): poll s_prog, gather eligible rows from the ring
        //   (row r eligible when prog >= r+64), store to HBM with no vmcnt
        //   drain (stores retire asynchronously), publish s_fprog[w].
        // Ring lifetime: row r's lane-l fragment (slot (r+l)&127, tick r+l)
        //   is overwritten at tick r+l+128 -> scan group [T,T+15] needs rows
        //   <= T-113 flushed; back-pressure check (3 LDS reads/group) with
        //   typical lag ~70 rows vs 112-row bound => never triggers.
        __shared__ float c_ring[RING * NDIM];   // 128 KiB
        __shared__ float y_lds[LSEQ];           // 4 KiB
        __shared__ float f_lds[LSEQ];           // 4 KiB
        __shared__ int   s_prog;                // completed ticks
        __shared__ int   s_fprog[3];            // per flush-wave next row

        if (tid == 0) s_prog = 0;
        if (tid < 3)  s_fprog[tid] = tid;
        for (int i = tid; i < LSEQ; i += 256) f_lds[i] = f[i];
        __syncthreads();                        // the ONLY barrier in block 0

        if (tid < 64) {
            // ---------------- wave 0: the scan ----------------
            const int l = tid;
            float rr[4], cc[4], baseE[4];
            #pragma unroll
            for (int e = 0; e < 4; ++e) {
                rr[e] = Bvec[4 * l + e];
                cc[e] = init_state[4 * l + e];
                baseE[e] = (float)(4 * l + 1 + e);   // (i+1)
            }
            float T = 0.0f, S = 0.0f, ssf = 0.0f, yacc = 0.0f;
            float E = (float)(-2 * l);               // E = 2(k0+1) after +=2
            float fcur = f_lds[l];
            float fnxt = f_lds[64 + l];
            float ssfv = fcur * frcp((float)(l + 1)); // ss_m*f_m, chunk 0

#define PUBLISH(V)                                                            \
  { asm volatile("s_waitcnt lgkmcnt(0)" ::: "memory");                        \
    *(volatile int*)&s_prog = (V); }

#define BACKPRESSURE(TB)                                                      \
  { const int need = (TB) - 112;                                              \
    for (;;) {                                                                \
      int m0 = *(volatile int*)&s_fprog[0];                                   \
      int m1 = *(volatile int*)&s_fprog[1];                                   \
      int m2 = *(volatile int*)&s_fprog[2];                                   \
      int mm = m0 < m1 ? m0 : m1; mm = mm < m2 ? mm : m2;                     \
      if (mm >= need) break;                                                  \
      __builtin_amdgcn_s_sleep(1);                                            \
    } }

// PHASE: 0 = ramp-up (act iff t>=l), 1 = steady (all), 2 = ramp-down (t-l<LSEQ)
#define SCAN_TICK(T_, RL_, PHASE)                                             \
  {                                                                           \
    const int t_ = (T_);                                                      \
    float inj = __int_as_float(__builtin_amdgcn_readlane(                     \
        __float_as_int(ssfv), (RL_)));                                        \
    T    = dpp_shr1_z(T);                                                     \
    S    = dpp_shr1_z(S);                                                     \
    yacc = dpp_shr1_z(yacc);                                                  \
    ssf  = dpp_shr1_inj(inj, ssf);                                            \
    E += 2.0f;                                                                \
    float h = frcp(E);                                                        \
    bool act = (PHASE == 1) ||                                                \
               ((PHASE == 0) ? (t_ >= l) : (t_ - l < LSEQ));                  \
    if (act) {                                                                \
      _Pragma("unroll")                                                       \
      for (int e = 0; e < 4; ++e) {                                           \
        float d    = fmaf(h, baseE[e], 1.0f);                                 \
        float invd = frcp(d);                                                 \
        float w    = fmaf(2.0f - d, cc[e], rr[e] * fmaf(-h, T, ssf));         \
        T = fmaf(rr[e], cc[e], T);                                            \
        float num = fmaf(-h * rr[e], S, w);                                   \
        float cn  = num * invd;                                               \
        S = fmaf(rr[e], cn, S);                                               \
        cc[e] = cn;                                                           \
      }                                                                       \
      yacc += (cc[0] + cc[1]) + (cc[2] + cc[3]);                              \
      v4f cv = { cc[0], cc[1], cc[2], cc[3] };                                \
      *reinterpret_cast<v4f*>(&c_ring[(t_ & (RING - 1)) * NDIM + 4 * l]) = cv;\
      y_lds[t_ - l] = yacc;  /* all lanes; lane 63 (full sum) lands last */   \
    }                                                                         \
  }

            int tb = 0;
            // ---- chunk 0: ramp-up, ticks 0..63
            for (int q = 0; q < 4; ++q) {
                #pragma unroll
                for (int g = 0; g < GT; ++g) SCAN_TICK(tb + g, q * GT + g, 0);
                PUBLISH(tb + GT);
                tb += GT;
            }
            // ---- chunks 1..15: steady, ticks 64..1023
            for (int ch = 1; ch < 16; ++ch) {
                fcur = fnxt;
                int idx = ch * 64 + 64 + l;
                fnxt = f_lds[(idx < LSEQ) ? idx : 0];   // stale value unused
                ssfv = fcur * frcp((float)(ch * 64 + l + 1));
                for (int q = 0; q < 4; ++q) {
                    BACKPRESSURE(tb);
                    #pragma unroll
                    for (int g = 0; g < GT; ++g) SCAN_TICK(tb + g, q * GT + g, 1);
                    PUBLISH(tb + GT);
                    tb += GT;
                }
            }
            // ---- ramp-down, ticks 1024..1087
            for (int q = 0; q < 4; ++q) {
                BACKPRESSURE(tb);
                #pragma unroll
                for (int g = 0; g < GT; ++g) SCAN_TICK(tb + g, q * GT + g, 2);
                PUBLISH(tb + GT);
                tb += GT;
            }
#undef SCAN_TICK
#undef PUBLISH
#undef BACKPRESSURE
        } else {
            // ---------------- waves 1-3: flush engines ----------------
            const int wv   = tid >> 6;        // 1..3
            const int lane = tid & 63;
            for (int r = wv - 1; r < LSEQ; r += 3) {
                while (*(volatile int*)&s_prog < r + 64)
                    __builtin_amdgcn_s_sleep(1);
                int slot = (r + lane) & (RING - 1);
                v4f dv = *reinterpret_cast<const v4f*>(
                    &c_ring[slot * NDIM + 4 * lane]);
                float yv = y_lds[r];
                __builtin_nontemporal_store(dv,
                    reinterpret_cast<v4f*>(
                        out + O_C + (size_t)r * NDIM + 4 * lane));
                if (lane == 0)
                    __builtin_nontemporal_store(yv, out + O_Y + r);
                asm volatile("" ::: "memory");
                *(volatile int*)&s_fprog[wv - 1] = r + 3;
            }
        }
    } else {
        // ================= GBT_A / GBT_B for k = bid-1, closed form =========
        // M[i,j] = -h r_i r_j/(d_i d_j) * W(j+1,i-1), W = P(i-1)/P(j),
        // P(p) = prod_{m<=p} g_m, g_m = (1-h m)/d_m.  Ad = 2M - I.
        // P ratios via log2-space prefix sums; exact zeros and signs tracked
        // structurally in a packed int prefix.
        const int k = bid - 1;
        const int lane = tid & 63;
        const int wave = tid >> 6;
        const float kp = (float)(k + 1);
        const float ss = 1.0f / kp;
        const float h  = 0.5f * ss;

        __shared__ float s_cc[NDIM], s_rowco[NDIM], s_diag[NDIM], s_Lp[NDIM];
        __shared__ int   s_NZp[NDIM];
        __shared__ float s_wL[4];
        __shared__ int   s_wNZ[4];

        const int i = tid;
        const float r    = Bvec[i];
        const float dd   = fmaf(h, (float)(i + 1), 1.0f);
        const float invd = 1.0f / dd;
        const float g    = (1.0f - h * (float)i) * invd;

        const int zer = (g == 0.0f) ? 1 : 0;
        const int neg = (g < 0.0f) ? 1 : 0;
        float sL = zer ? 0.0f : hlog2(fabsf(g));
        int   sNZ = neg | (zer << 16);

        // inclusive scan: intra-wave shfl + cross-wave totals
        #pragma unroll
        for (int off = 1; off < 64; off <<= 1) {
            float tL  = __shfl_up(sL, off);
            int   tNZ = __shfl_up(sNZ, off);
            if (lane >= off) { sL += tL; sNZ += tNZ; }
        }
        if (lane == 63) { s_wL[wave] = sL; s_wNZ[wave] = sNZ; }
        __syncthreads();
        for (int ww = 0; ww < wave; ++ww) { sL += s_wL[ww]; sNZ += s_wNZ[ww]; }

        s_Lp[i]    = sL;
        s_NZp[i]   = sNZ;
        s_cc[i]    = r * invd;
        s_rowco[i] = -2.0f * h * r * invd;     // = -ss*r*invd
        s_diag[i]  = fmaf(2.0f, invd, -1.0f);
        __syncthreads();

        // GBT_B: Bd_i = ss*r_i*invd_i * P(i-1) = -rowco_i * P(i-1)
        {
            float P;
            if (i == 0) P = 1.0f;
            else {
                float Lw = s_Lp[i - 1]; int nzw = s_NZp[i - 1];
                P = (nzw >> 16) ? 0.0f : hexp2(Lw);
                if (nzw & 1) P = -P;
            }
            out[O_B + (size_t)k * NDIM + i] = -s_rowco[i] * P;
        }

        // per-lane column constants (fixed across rows)
        float Lj[4], ccj[4]; int NZj[4];
        #pragma unroll
        for (int e = 0; e < 4; ++e) {
            int j = 4 * lane + e;
            Lj[e]  = s_Lp[j];
            NZj[e] = s_NZp[j];
            ccj[e] = s_cc[j];
        }

        const int i0 = wave * 64;
        float* outA = out + O_A + (size_t)k * (NDIM * NDIM) + 4 * lane;
        #pragma unroll 4
        for (int ir = 0; ir < 64; ++ir) {
            const int irow = i0 + ir;
            const int ip = (irow > 0) ? (irow - 1) : 0;
            const float Lpi = s_Lp[ip];
            const int   NZi = s_NZp[ip];
            const float rc  = s_rowco[irow];
            const float dg  = s_diag[irow];
            float v[4];
            #pragma unroll
            for (int e = 0; e < 4; ++e) {
                const int j = 4 * lane + e;
                float wv = hexp2(Lpi - Lj[e]);
                int nzd = NZi - NZj[e];
                wv = (nzd >> 16) ? 0.0f : wv;
                wv = (nzd & 1) ? -wv : wv;
                float val = rc * ccj[e] * wv;
                v[e] = (j < irow) ? val : ((j == irow) ? dg : 0.0f);
            }
            v4f vv = { v[0], v[1], v[2], v[3] };
            __builtin_nontemporal_store(
                vv, reinterpret_cast<v4f*>(outA + (size_t)irow * NDIM));
        }
    }
}

extern "C" void kernel_launch(void* const* d_in, const int* in_sizes, int n_in,
                              void* d_out, int out_size, void* d_ws, size_t ws_size,
                              hipStream_t stream) {
    (void)in_sizes; (void)n_in; (void)d_ws; (void)ws_size; (void)out_size;
    const float* f    = (const float*)d_in[0];
    const float* init = (const float*)d_in[1];
    const float* Bv   = (const float*)d_in[3];   // B = r[:,None]
    float* outp       = (float*)d_out;
    hippo_main<<<1 + LSEQ, 256, 0, stream>>>(f, init, Bv, outp);
}

// Round 8
// 366.704 us; speedup vs baseline: 1.2862x; 1.0452x over previous
//
#include <hip/hip_runtime.h>

#define LSEQ 1024
#define NDIM 256

// output layout (floats): c_all | y_all | GBT_A | GBT_B
#define O_C 0
#define O_Y (LSEQ * NDIM)                      // 262144
#define O_A (O_Y + LSEQ)                       // 263168
#define O_B (O_A + (size_t)LSEQ * NDIM * NDIM) // 67372032

#define RING 128     // c ring slots (1KB each)
#define GT   16      // ticks per group (publish/gate granularity)

typedef float v4f __attribute__((ext_vector_type(4)));
typedef float v2f __attribute__((ext_vector_type(2)));

static __device__ __forceinline__ float frcp(float x) {
    return __builtin_amdgcn_rcpf(x);
}
static __device__ __forceinline__ float hlog2(float x) {
    return __builtin_amdgcn_logf(x);
}
static __device__ __forceinline__ float hexp2(float x) {
    return __builtin_amdgcn_exp2f(x);
}

// in-place wave shift-right-by-1, lane 0 := 0 (bound_ctrl zero-fill)
static __device__ __forceinline__ float dpp_shr1_z(float x) {
    int r = __builtin_amdgcn_update_dpp(
        __float_as_int(x), __float_as_int(x), 0x138 /*WAVE_SHR1*/, 0xF, 0xF, true);
    return __int_as_float(r);
}
// shift-right-by-1 with lane 0 := inject (old-operand form)
static __device__ __forceinline__ float dpp_shr1_inj(float inject, float src) {
    int r = __builtin_amdgcn_update_dpp(
        __float_as_int(inject), __float_as_int(src), 0x138, 0xF, 0xF, false);
    return __int_as_float(r);
}

// bounded spin (fail loudly rather than hang if protocol breaks)
#define GATE(VAR, NEED)                                                      \
  { const int need_ = (NEED);                                                \
    for (int sp_ = 0; sp_ < (1 << 22); ++sp_) {                              \
      if (*(volatile int*)&(VAR) >= need_) break;                            \
      __builtin_amdgcn_s_sleep(1);                                           \
    } }

#define PUBLISH(VAR, V)                                                      \
  { asm volatile("s_waitcnt lgkmcnt(0)" ::: "memory");                       \
    *(volatile int*)&(VAR) = (V); }

__global__ __launch_bounds__(256) void hippo_main(
    const float* __restrict__ f,
    const float* __restrict__ init_state,
    const float* __restrict__ Bvec,   // = r_i = sqrt(2i+1)
    float* __restrict__ out)
{
    const int tid = threadIdx.x;
    const int bid = blockIdx.x;

    if (bid == 0) {
        // ========== sequential scan: 2-wave skewed systolic =================
        // The scan is per-wave ISSUE-bound (~6.2 cy/instr measured R7), so
        // split it: wave A owns elems 0..127 (2/lane), wave B elems 128..255.
        // Intra-wave handoff stays DPP; the single wave boundary passes
        // (T,S,ssf,yacc) through b_ring in LDS: A.lane63 writes 1 b128/tick,
        // B prefetches 16 entries/group (broadcast reads) and cndmask-blends
        // into lane 0. B lags A by ~80-96 ticks via group-granular progress
        // counters. Waves 2/3 flush half-rows (512B) from the c ring.
        // c_all is bit-identical to R7 (same per-element op sequence; exact
        // value pass-through at the boundary); y is reassociated (~1e-6).
        __shared__ float c_ring[RING * NDIM];   // 128 KiB [slot][elem]
        __shared__ float f_lds[LSEQ];           // 4 KiB
        __shared__ float y_lds[LSEQ];           // 4 KiB
        __shared__ v4f   b_ring[RING];          // 2 KiB boundary (T,S,ssf,ya)
        __shared__ int   s_p0, s_p1, s_f0, s_f1;

        const int wv = tid >> 6;
        const int l  = tid & 63;

        if (tid == 0) { s_p0 = 0; s_p1 = 0; s_f0 = 0; s_f1 = 0; }
        for (int i = tid; i < LSEQ; i += 256) f_lds[i] = f[i];
        __syncthreads();                        // only barrier in block 0

        if (wv == 0) {
            // ---------------- wave A: scan elems 0..127 ----------------
            float rr0 = Bvec[2 * l],     rr1 = Bvec[2 * l + 1];
            float c0  = init_state[2*l], c1  = init_state[2*l + 1];
            const float bE0 = (float)(2 * l + 1), bE1 = (float)(2 * l + 2);
            float T = 0.f, S = 0.f, ssf = 0.f, ya = 0.f;
            float E = (float)(-2 * l);          // E = 2(k0+1) after +=2
            float fcur = f_lds[l], fnxt = f_lds[64 + l];
            float ssfv = fcur * frcp((float)(l + 1));

#define TICK_A(T_, ACT)                                                       \
  { const int t_ = (T_);                                                      \
    float inj = __int_as_float(__builtin_amdgcn_readlane(                     \
        __float_as_int(ssfv), t_ & 63));                                      \
    T = dpp_shr1_z(T); S = dpp_shr1_z(S); ya = dpp_shr1_z(ya);                \
    ssf = dpp_shr1_inj(inj, ssf);                                             \
    E += 2.0f; float h = frcp(E);                                             \
    if (ACT) {                                                                \
      float d0 = fmaf(h, bE0, 1.0f); float i0 = frcp(d0);                     \
      float w0 = fmaf(2.0f - d0, c0, rr0 * fmaf(-h, T, ssf));                 \
      T = fmaf(rr0, c0, T);                                                   \
      float n0 = fmaf(-h * rr0, S, w0); c0 = n0 * i0;                         \
      S = fmaf(rr0, c0, S);                                                   \
      float d1 = fmaf(h, bE1, 1.0f); float i1 = frcp(d1);                     \
      float w1 = fmaf(2.0f - d1, c1, rr1 * fmaf(-h, T, ssf));                 \
      T = fmaf(rr1, c1, T);                                                   \
      float n1 = fmaf(-h * rr1, S, w1); c1 = n1 * i1;                         \
      S = fmaf(rr1, c1, S);                                                   \
      ya += (c0 + c1);                                                        \
      v2f cv = { c0, c1 };                                                    \
      *reinterpret_cast<v2f*>(&c_ring[(t_ & 127) * NDIM + 2 * l]) = cv;       \
      if (l == 63) { v4f bw = { T, S, ssf, ya };                              \
                     b_ring[t_ & 127] = bw; }                                 \
    } }

            int tb = 0;
            for (int grp = 0; grp < 4; ++grp, tb += GT) {       // ramp-up
                #pragma unroll
                for (int g = 0; g < GT; ++g) TICK_A(tb + g, (tb + g) >= l);
                PUBLISH(s_p0, tb + GT);
            }
            for (int grp = 4; grp < 64; ++grp, tb += GT) {      // steady
                if ((tb & 63) == 0) {
                    fcur = fnxt;
                    int idx = tb + 64 + l;
                    fnxt = f_lds[(idx < LSEQ) ? idx : 0];
                    ssfv = fcur * frcp((float)(tb + l + 1));
                }
                if (tb >= 128) GATE(s_f0, tb - 112);   // c-ring half-0 reuse
                if (tb >= 176) GATE(s_p1, tb - 175);   // b-ring reuse
                #pragma unroll
                for (int g = 0; g < GT; ++g) TICK_A(tb + g, true);
                PUBLISH(s_p0, tb + GT);
            }
            for (int grp = 64; grp < 68; ++grp, tb += GT) {     // ramp-down
                GATE(s_f0, tb - 112);
                GATE(s_p1, tb - 175);
                #pragma unroll
                for (int g = 0; g < GT; ++g) TICK_A(tb + g, (tb + g) - l < LSEQ);
                PUBLISH(s_p0, tb + GT);
            }
#undef TICK_A
        } else if (wv == 1) {
            // ---------------- wave B: scan elems 128..255 ----------------
            float rr0 = Bvec[128 + 2 * l],     rr1 = Bvec[128 + 2 * l + 1];
            float c0  = init_state[128 + 2*l], c1  = init_state[128 + 2*l + 1];
            const float bE0 = (float)(128 + 2 * l + 1);
            const float bE1 = (float)(128 + 2 * l + 2);
            float T = 0.f, S = 0.f, ssf = 0.f, ya = 0.f;
            float E = (float)(-2 * l);
            const bool l0 = (l == 0);

#define TICK_B(T_, G_, ACT)                                                   \
  { const int t_ = (T_);                                                      \
    T = dpp_shr1_z(T); S = dpp_shr1_z(S); ya = dpp_shr1_z(ya);                \
    ssf = dpp_shr1_z(ssf);                                                    \
    { v4f bb = bbuf[G_];                                                      \
      if (l0) { T = bb.x; S = bb.y; ssf = bb.z; ya = bb.w; } }                \
    E += 2.0f; float h = frcp(E);                                             \
    if (ACT) {                                                                \
      float d0 = fmaf(h, bE0, 1.0f); float i0 = frcp(d0);                     \
      float w0 = fmaf(2.0f - d0, c0, rr0 * fmaf(-h, T, ssf));                 \
      T = fmaf(rr0, c0, T);                                                   \
      float n0 = fmaf(-h * rr0, S, w0); c0 = n0 * i0;                         \
      S = fmaf(rr0, c0, S);                                                   \
      float d1 = fmaf(h, bE1, 1.0f); float i1 = frcp(d1);                     \
      float w1 = fmaf(2.0f - d1, c1, rr1 * fmaf(-h, T, ssf));                 \
      T = fmaf(rr1, c1, T);                                                   \
      float n1 = fmaf(-h * rr1, S, w1); c1 = n1 * i1;                         \
      S = fmaf(rr1, c1, S);                                                   \
      ya += (c0 + c1);                                                        \
      v2f cv = { c0, c1 };                                                    \
      *reinterpret_cast<v2f*>(&c_ring[(t_ & 127) * NDIM + 128 + 2 * l]) = cv; \
      y_lds[t_ - l] = ya;                                                     \
    } }

#define PREFETCH_B(TB)                                                        \
    v4f bbuf[GT];                                                             \
    _Pragma("unroll")                                                         \
    for (int g = 0; g < GT; ++g)                                              \
        bbuf[g] = b_ring[((TB) + 63 + g) & 127];

            int tb = 0;
            for (int grp = 0; grp < 4; ++grp, tb += GT) {       // ramp-up
                GATE(s_p0, tb + 79);
                PREFETCH_B(tb);
                #pragma unroll
                for (int g = 0; g < GT; ++g) TICK_B(tb + g, g, (tb + g) >= l);
                PUBLISH(s_p1, tb + GT);
            }
            for (int grp = 4; grp < 64; ++grp, tb += GT) {      // steady
                GATE(s_p0, tb + 79);
                if (tb >= 128) GATE(s_f1, tb - 112);
                PREFETCH_B(tb);
                #pragma unroll
                for (int g = 0; g < GT; ++g) TICK_B(tb + g, g, true);
                PUBLISH(s_p1, tb + GT);
            }
            for (int grp = 64; grp < 68; ++grp, tb += GT) {     // ramp-down
                { int need = tb + 79; if (need > 1088) need = 1088;
                  GATE(s_p0, need); }
                GATE(s_f1, tb - 112);
                PREFETCH_B(tb);
                #pragma unroll
                for (int g = 0; g < GT; ++g) TICK_B(tb + g, g, (tb + g) - l < LSEQ);
                PUBLISH(s_p1, tb + GT);
            }
#undef TICK_B
#undef PREFETCH_B
        } else if (wv == 2) {
            // ---------------- flush half-0 (elems 0..127) ----------------
            for (int r = 0; r < LSEQ; r += GT) {
                GATE(s_p0, r + 79);                   // rows r..r+15 complete
                #pragma unroll
                for (int q = 0; q < GT; ++q) {
                    int rw = r + q;
                    int slot = (rw + l) & 127;
                    v2f dv = *reinterpret_cast<const v2f*>(
                        &c_ring[slot * NDIM + 2 * l]);
                    __builtin_nontemporal_store(dv,
                        reinterpret_cast<v2f*>(
                            out + O_C + (size_t)rw * NDIM + 2 * l));
                }
                asm volatile("s_waitcnt lgkmcnt(0)" ::: "memory");
                *(volatile int*)&s_f0 = r + GT;
            }
        } else {
            // ---------------- flush half-1 (elems 128..255) + y ----------
            for (int r = 0; r < LSEQ; r += GT) {
                GATE(s_p1, r + 79);
                #pragma unroll
                for (int q = 0; q < GT; ++q) {
                    int rw = r + q;
                    int slot = (rw + l) & 127;
                    v2f dv = *reinterpret_cast<const v2f*>(
                        &c_ring[slot * NDIM + 128 + 2 * l]);
                    __builtin_nontemporal_store(dv,
                        reinterpret_cast<v2f*>(
                            out + O_C + (size_t)rw * NDIM + 128 + 2 * l));
                }
                if (l < GT) {
                    float yv = y_lds[r + l];
                    __builtin_nontemporal_store(yv, out + O_Y + r + l);
                }
                asm volatile("s_waitcnt lgkmcnt(0)" ::: "memory");
                *(volatile int*)&s_f1 = r + GT;
            }
        }
    } else {
        // ================= GBT_A / GBT_B for k = bid-1, closed form =========
        // M[i,j] = -h r_i r_j/(d_i d_j) * W(j+1,i-1), W = P(i-1)/P(j),
        // P(p) = prod_{m<=p} g_m, g_m = (1-h m)/d_m.  Ad = 2M - I.
        // P ratios via log2-space prefix sums; exact zeros and signs tracked
        // structurally in a packed int prefix.
        const int k = bid - 1;
        const int lane = tid & 63;
        const int wave = tid >> 6;
        const float kp = (float)(k + 1);
        const float ss = 1.0f / kp;
        const float h  = 0.5f * ss;

        __shared__ float s_cc[NDIM], s_rowco[NDIM], s_diag[NDIM], s_Lp[NDIM];
        __shared__ int   s_NZp[NDIM];
        __shared__ float s_wL[4];
        __shared__ int   s_wNZ[4];

        const int i = tid;
        const float r    = Bvec[i];
        const float dd   = fmaf(h, (float)(i + 1), 1.0f);
        const float invd = 1.0f / dd;
        const float g    = (1.0f - h * (float)i) * invd;

        const int zer = (g == 0.0f) ? 1 : 0;
        const int neg = (g < 0.0f) ? 1 : 0;
        float sL = zer ? 0.0f : hlog2(fabsf(g));
        int   sNZ = neg | (zer << 16);

        // inclusive scan: intra-wave shfl + cross-wave totals
        #pragma unroll
        for (int off = 1; off < 64; off <<= 1) {
            float tL  = __shfl_up(sL, off);
            int   tNZ = __shfl_up(sNZ, off);
            if (lane >= off) { sL += tL; sNZ += tNZ; }
        }
        if (lane == 63) { s_wL[wave] = sL; s_wNZ[wave] = sNZ; }
        __syncthreads();
        for (int ww = 0; ww < wave; ++ww) { sL += s_wL[ww]; sNZ += s_wNZ[ww]; }

        s_Lp[i]    = sL;
        s_NZp[i]   = sNZ;
        s_cc[i]    = r * invd;
        s_rowco[i] = -2.0f * h * r * invd;     // = -ss*r*invd
        s_diag[i]  = fmaf(2.0f, invd, -1.0f);
        __syncthreads();

        // GBT_B: Bd_i = ss*r_i*invd_i * P(i-1) = -rowco_i * P(i-1)
        {
            float P;
            if (i == 0) P = 1.0f;
            else {
                float Lw = s_Lp[i - 1]; int nzw = s_NZp[i - 1];
                P = (nzw >> 16) ? 0.0f : hexp2(Lw);
                if (nzw & 1) P = -P;
            }
            out[O_B + (size_t)k * NDIM + i] = -s_rowco[i] * P;
        }

        // per-lane column constants (fixed across rows)
        float Lj[4], ccj[4]; int NZj[4];
        #pragma unroll
        for (int e = 0; e < 4; ++e) {
            int j = 4 * lane + e;
            Lj[e]  = s_Lp[j];
            NZj[e] = s_NZp[j];
            ccj[e] = s_cc[j];
        }

        const int i0 = wave * 64;
        float* outA = out + O_A + (size_t)k * (NDIM * NDIM) + 4 * lane;
        #pragma unroll 4
        for (int ir = 0; ir < 64; ++ir) {
            const int irow = i0 + ir;
            const int ip = (irow > 0) ? (irow - 1) : 0;
            const float Lpi = s_Lp[ip];
            const int   NZi = s_NZp[ip];
            const float rc  = s_rowco[irow];
            const float dg  = s_diag[irow];
            float v[4];
            #pragma unroll
            for (int e = 0; e < 4; ++e) {
                const int j = 4 * lane + e;
                float wvv = hexp2(Lpi - Lj[e]);
                int nzd = NZi - NZj[e];
                wvv = (nzd >> 16) ? 0.0f : wvv;
                wvv = (nzd & 1) ? -wvv : wvv;
                float val = rc * ccj[e] * wvv;
                v[e] = (j < irow) ? val : ((j == irow) ? dg : 0.0f);
            }
            v4f vv = { v[0], v[1], v[2], v[3] };
            __builtin_nontemporal_store(
                vv, reinterpret_cast<v4f*>(outA + (size_t)irow * NDIM));
        }
    }
}

extern "C" void kernel_launch(void* const* d_in, const int* in_sizes, int n_in,
                              void* d_out, int out_size, void* d_ws, size_t ws_size,
                              hipStream_t stream) {
    (void)in_sizes; (void)n_in; (void)d_ws; (void)ws_size; (void)out_size;
    const float* f    = (const float*)d_in[0];
    const float* init = (const float*)d_in[1];
    const float* Bv   = (const float*)d_in[3];   // B = r[:,None]
    float* outp       = (float*)d_out;
    hippo_main<<<1 + LSEQ, 256, 0, stream>>>(f, init, Bv, outp);
}